// Round 11
// baseline (149.233 us; speedup 1.0000x reference)
//
#include <hip/hip_runtime.h>

#define NPIX 704
#define NIMG 24
#define NB 4
#define NCAM 6
#define DB 59
#define CT 64
#define P_TOT (NIMG*NPIX*DB)   // 996864
#define NVOX 65536             // 4 batches * 128*128 (gz==0 only)
#define SLC 8                  // histogram slices (contention spreading)
#define NKEY (NVOX*SLC)        // 524288
#define CHUNK 64
#define SCAN_BLKS 512          // NKEY / 1024
#define MPIX (NIMG*NPIX)       // 16896

typedef unsigned short u16;
typedef __attribute__((ext_vector_type(8))) unsigned short u16x8;
typedef __attribute__((ext_vector_type(4))) __bf16 bf16x4;
typedef __attribute__((ext_vector_type(8))) __bf16 bf16x8;
typedef __attribute__((ext_vector_type(4))) float f32x4;

__device__ inline u16 f2bf(float f) {          // RN float->bf16
  unsigned u = __float_as_uint(f);
  u += 0x7FFFu + ((u >> 16) & 1u);
  return (u16)(u >> 16);
}
__device__ inline float bf2f(u16 s) {
  return __uint_as_float(((unsigned)s) << 16);
}

// ---------------------------------------------------------------------------
// Kernel 1: W -> bf16 hi/lo (blocks 0..255) + per-(b,n) matrix prep (block 256)
// ---------------------------------------------------------------------------
__device__ inline void inv3(const double a[9], double o[9]) {
  double c0 = a[4]*a[8] - a[5]*a[7];
  double c1 = a[3]*a[8] - a[5]*a[6];
  double c2 = a[3]*a[7] - a[4]*a[6];
  double det = a[0]*c0 - a[1]*c1 + a[2]*c2;
  double id = 1.0 / det;
  o[0] =  c0 * id;
  o[1] = (a[2]*a[7] - a[1]*a[8]) * id;
  o[2] = (a[1]*a[5] - a[2]*a[4]) * id;
  o[3] = -c1 * id;
  o[4] = (a[0]*a[8] - a[2]*a[6]) * id;
  o[5] = (a[2]*a[3] - a[0]*a[5]) * id;
  o[6] =  c2 * id;
  o[7] = (a[1]*a[6] - a[0]*a[7]) * id;
  o[8] = (a[0]*a[4] - a[1]*a[3]) * id;
}

__global__ __launch_bounds__(256) void prep_convw(
    const float* __restrict__ rots, const float* __restrict__ trans,
    const float* __restrict__ intr, const float* __restrict__ prot,
    const float* __restrict__ ptra, float* __restrict__ mats,
    const float* __restrict__ Wd, u16* __restrict__ Wh, u16* __restrict__ Wl) {
  if (blockIdx.x < 256) {
    int idx = blockIdx.x * 256 + threadIdx.x;   // 128*512 entries, idx = o*512+k
    int o = idx >> 9;
    float f = (o < 123) ? Wd[idx] : 0.f;
    u16 h = f2bf(f);
    Wh[idx] = h;
    Wl[idx] = f2bf(f - bf2f(h));
    return;
  }
  int bn = threadIdx.x;
  if (bn >= NIMG) return;
  double pr[9], ik[9];
  for (int i = 0; i < 9; i++) { pr[i] = prot[bn*9 + i]; ik[i] = intr[bn*9 + i]; }
  double Minv[9], Kinv[9];
  inv3(pr, Minv);
  inv3(ik, Kinv);
  float* m = mats + bn*24;
  for (int i = 0; i < 9; i++) m[i] = (float)Minv[i];
  float kf[9];
  for (int i = 0; i < 9; i++) kf[i] = (float)Kinv[i];
  {
#pragma clang fp contract(off)
    for (int i = 0; i < 3; i++)
      for (int j = 0; j < 3; j++) {
        float s = rots[bn*9 + i*3 + 0] * kf[0*3 + j];
        s = s + rots[bn*9 + i*3 + 1] * kf[1*3 + j];
        s = s + rots[bn*9 + i*3 + 2] * kf[2*3 + j];
        m[9 + i*3 + j] = s;
      }
  }
  m[18] = ptra[bn*3 + 0]; m[19] = ptra[bn*3 + 1]; m[20] = ptra[bn*3 + 2];
  m[21] = trans[bn*3 + 0]; m[22] = trans[bn*3 + 1]; m[23] = trans[bn*3 + 2];
}

// ---------------------------------------------------------------------------
// Kernel 2: fused MFMA GEMM (bf16 hi/lo 3-term ~= fp32) + softmax.
// Tile 32 pix x 128 o x K=512, BK=64; 528 blocks, 4 waves (2 pix-half x 2
// o-half), each wave 1x4 frags of mfma_f32_16x16x32_bf16, 3-term.
// LDS: padded rows of 144B (bank rotation 4/row, <=2-way everywhere), NO xor.
//   Ah[32][144] @0, Al @4608, Bh[128][144] @9216, Bl @27648; total 46080 B.
// Epilogue overlays F[32][132] fp32 @0.
// ---------------------------------------------------------------------------
__global__ __launch_bounds__(256) void gemm_fused(const float* __restrict__ x,
    const u16* __restrict__ Wh, const u16* __restrict__ Wl,
    const float* __restrict__ bd,
    float* __restrict__ depth_ws, float* __restrict__ img_ws) {
  __shared__ __attribute__((aligned(16))) unsigned char smem[46080];
  int t = threadIdx.x;
  int l = t & 63, wid = t >> 6;
  int wr = wid >> 1, wc = wid & 1;
  int pixbase = blockIdx.x << 5;       // 704 = 22*32: tile stays in one image
  int bn = pixbase / NPIX;
  int pix0 = pixbase - bn * NPIX;
  const float* xb = x + (size_t)bn * 512 * NPIX + pix0;

  f32x4 zero4 = {0.f, 0.f, 0.f, 0.f};
  f32x4 acc[4];
#pragma unroll
  for (int ni = 0; ni < 4; ni++) acc[ni] = zero4;

  for (int kb = 0; kb < 512; kb += 64) {
    // ---- stage A: x[64c][32pix] -> Ah/Al[pix][c]; c-major lanes so that
    // LDS write banks vary with (t&15): 2-way max. ----
    {
      int c0 = (t & 15) << 2;            // 0..60
      int pixt = (t >> 4) << 1;          // 0..30
      float2 v0 = *(const float2*)&xb[(size_t)(kb + c0 + 0) * NPIX + pixt];
      float2 v1 = *(const float2*)&xb[(size_t)(kb + c0 + 1) * NPIX + pixt];
      float2 v2 = *(const float2*)&xb[(size_t)(kb + c0 + 2) * NPIX + pixt];
      float2 v3 = *(const float2*)&xb[(size_t)(kb + c0 + 3) * NPIX + pixt];
#pragma unroll
      for (int j = 0; j < 2; ++j) {
        float f0 = j ? v0.y : v0.x;
        float f1 = j ? v1.y : v1.x;
        float f2 = j ? v2.y : v2.x;
        float f3 = j ? v3.y : v3.x;
        __bf16 h0 = (__bf16)f0, h1 = (__bf16)f1, h2 = (__bf16)f2, h3 = (__bf16)f3;
        bf16x4 hv = {h0, h1, h2, h3};
        bf16x4 lv = {(__bf16)(f0 - (float)h0), (__bf16)(f1 - (float)h1),
                     (__bf16)(f2 - (float)h2), (__bf16)(f3 - (float)h3)};
        int row = pixt + j;
        *(bf16x4*)(smem + row * 144 + c0 * 2) = hv;
        *(bf16x4*)(smem + 4608 + row * 144 + c0 * 2) = lv;
      }
    }
    // ---- stage B: Wh/Wl[o][k] (k-contiguous rows) ----
    {
      int o = t & 127;
      int kh = (t >> 7) << 5;            // 0 or 32
      const u16* sh = Wh + (size_t)o * 512 + kb + kh;
      const u16* sl = Wl + (size_t)o * 512 + kb + kh;
#pragma unroll
      for (int i = 0; i < 4; ++i) {
        int kkb = (kh + (i << 3)) * 2;
        *(u16x8*)(smem + 9216 + o * 144 + kkb) = *(const u16x8*)(sh + (i << 3));
        *(u16x8*)(smem + 27648 + o * 144 + kkb) = *(const u16x8*)(sl + (i << 3));
      }
    }
    __syncthreads();
    // ---- compute: 2 k-halves x 4 frags x 3 MFMA ----
#pragma unroll
    for (int h = 0; h < 2; ++h) {
      int kk2 = (h * 32 + ((l >> 4) << 3)) * 2;     // byte offset in row
      int arow = (wr << 4) + (l & 15);
      bf16x8 ah = *(const bf16x8*)(smem + arow * 144 + kk2);
      bf16x8 al = *(const bf16x8*)(smem + 4608 + arow * 144 + kk2);
#pragma unroll
      for (int ni = 0; ni < 4; ++ni) {
        int o = (wc << 6) + (ni << 4) + (l & 15);
        bf16x8 bh_ = *(const bf16x8*)(smem + 9216 + o * 144 + kk2);
        bf16x8 bl_ = *(const bf16x8*)(smem + 27648 + o * 144 + kk2);
        acc[ni] = __builtin_amdgcn_mfma_f32_16x16x32_bf16(ah, bh_, acc[ni], 0, 0, 0);
        acc[ni] = __builtin_amdgcn_mfma_f32_16x16x32_bf16(ah, bl_, acc[ni], 0, 0, 0);
        acc[ni] = __builtin_amdgcn_mfma_f32_16x16x32_bf16(al, bh_, acc[ni], 0, 0, 0);
      }
    }
    __syncthreads();
  }

  // ---- epilogue: acc -> F[32][132], then wave softmax ----
  float* F = (float*)smem;
#pragma unroll
  for (int ni = 0; ni < 4; ++ni)
#pragma unroll
    for (int r = 0; r < 4; ++r) {
      int row = (wr << 4) + ((l >> 4) << 2) + r;
      int col = (wc << 6) + (ni << 4) + (l & 15);
      F[row * 132 + col] = acc[ni][r];
    }
  __syncthreads();

  int c = l;
  float bA = bd[c];
  float bI = bd[DB + c];
  for (int p = wid; p < 32; p += 4) {
    float fA = F[p * 132 + c] + bA;
    float fI = F[p * 132 + DB + c] + bI;
    float mv = (c < DB) ? fA : -3.4e38f;
#pragma unroll
    for (int ofs = 32; ofs > 0; ofs >>= 1) mv = fmaxf(mv, __shfl_xor(mv, ofs));
    float ev = (c < DB) ? expf(fA - mv) : 0.f;
    float sv = ev;
#pragma unroll
    for (int ofs = 32; ofs > 0; ofs >>= 1) sv += __shfl_xor(sv, ofs);
    size_t rec = (size_t)(pixbase + p) << 6;
    if (c < DB) depth_ws[rec + c] = ev / sv;
    img_ws[rec + c] = fI;
  }
}

// ---------------------------------------------------------------------------
// Kernel 3: geometry -> sliced key + rank via hist atomic.
// ---------------------------------------------------------------------------
__global__ __launch_bounds__(256) void geom_k(const float* __restrict__ mats,
    int2* __restrict__ pr, int* __restrict__ hist) {
  int wid = (blockIdx.x << 2) + (threadIdx.x >> 6);
  int lane = threadIdx.x & 63;
  int bn = wid / NPIX;
  int pix = wid - bn*NPIX;
  int b = bn / NCAM;
  int h = pix / 44, w = pix - h*44;
  const float* M = mats + bn*24;

  int code = -1;
  {
#pragma clang fp contract(off)
    float xs = (float)((double)w * (703.0 / 43.0));
    float ys = (float)(h * 17);
    float dval = (float)(lane + 1);
    float vx = xs - M[18], vy = ys - M[19], vz = dval - M[20];
    float qx = M[0]*vx + M[1]*vy + M[2]*vz;
    float qy = M[3]*vx + M[4]*vy + M[5]*vz;
    float qz = M[6]*vx + M[7]*vy + M[8]*vz;
    float rx = qx*qz, ry = qy*qz;
    float px = M[9]*rx  + M[10]*ry + M[11]*qz + M[21];
    float py = M[12]*rx + M[13]*ry + M[14]*qz + M[22];
    float pz = M[15]*rx + M[16]*ry + M[17]*qz + M[23];
    float gx = floorf((px - (-50.8f - 0.4f)) / 0.8f);
    float gy = floorf((py - (-50.8f - 0.4f)) / 0.8f);
    float gz = floorf((pz - (0.0f - 10.0f)) / 20.0f);
    bool kept = (lane < DB) && (gx >= 0.f) && (gx < 128.f) &&
                (gy >= 0.f) && (gy < 128.f) && (gz == 0.f);
    if (kept) code = (b << 14) + (int)gy * 128 + (int)gx;
  }

  if (lane < DB) {
    int key = -1, r = 0;
    if (code >= 0) {
      key = code * SLC + ((wid + lane) & (SLC - 1));
      r = atomicAdd(&hist[key], 1);
    }
    pr[(size_t)wid * DB + lane] = make_int2(key, r);
  }
}

// ---------------------------------------------------------------------------
// Kernels 4a/4b/4c: hierarchical exclusive scan of hist[NKEY].
// ---------------------------------------------------------------------------
__global__ __launch_bounds__(256) void scan1_k(const int* __restrict__ hist,
    int* __restrict__ blockSums) {
  __shared__ int red[256];
  int t = threadIdx.x;
  const int4* h4 = (const int4*)(hist + (blockIdx.x << 10));
  int4 v = h4[t];
  red[t] = v.x + v.y + v.z + v.w;
  __syncthreads();
  for (int ofs = 128; ofs > 0; ofs >>= 1) {
    if (t < ofs) red[t] += red[t + ofs];
    __syncthreads();
  }
  if (t == 0) blockSums[blockIdx.x] = red[0];
}

__global__ __launch_bounds__(512) void scan2_k(int* __restrict__ blockSums,
    int* __restrict__ totalK) {
  __shared__ int buf[2][512];
  int t = threadIdx.x;
  buf[0][t] = blockSums[t];
  __syncthreads();
  int src = 0;
  for (int ofs = 1; ofs < 512; ofs <<= 1) {
    int v = buf[src][t];
    if (t >= ofs) v += buf[src][t - ofs];
    buf[src ^ 1][t] = v;
    __syncthreads();
    src ^= 1;
  }
  blockSums[t] = (t == 0) ? 0 : buf[src][t - 1];
  if (t == 511) *totalK = buf[src][511];
}

__global__ __launch_bounds__(256) void scan3_k(int* __restrict__ hist,
    const int* __restrict__ blockSums) {
  __shared__ int buf[2][256];
  int t = threadIdx.x;
  int4* h4 = (int4*)(hist + (blockIdx.x << 10));
  int4 v = h4[t];
  int s = v.x + v.y + v.z + v.w;
  buf[0][t] = s;
  __syncthreads();
  int src = 0;
  for (int ofs = 1; ofs < 256; ofs <<= 1) {
    int vv = buf[src][t];
    if (t >= ofs) vv += buf[src][t - ofs];
    buf[src ^ 1][t] = vv;
    __syncthreads();
    src ^= 1;
  }
  int run = blockSums[blockIdx.x] + ((t == 0) ? 0 : buf[src][t - 1]);
  int4 o;
  o.x = run; run += v.x;
  o.y = run; run += v.y;
  o.z = run; run += v.z;
  o.w = run;
  h4[t] = o;
}

// ---------------------------------------------------------------------------
// Kernel 5: atomic-free placement: pos = offsets[key] + rank.
// ---------------------------------------------------------------------------
__global__ __launch_bounds__(256) void order_k(const int2* __restrict__ pr,
    const int* __restrict__ offsets, int2* __restrict__ sorted) {
  int p = blockIdx.x * 256 + threadIdx.x;
  if (p >= P_TOT) return;
  int2 e = pr[p];
  if (e.x >= 0) {
    int pos = offsets[e.x] + e.y;
    int bnpix = p / DB;
    int d = p - bnpix * DB;
    sorted[pos] = make_int2(e.x / SLC, (bnpix << 6) + d);
  }
}

// ---------------------------------------------------------------------------
// Kernel 6: segmented gather. One wave per CHUNK sorted points; lane = channel.
// ---------------------------------------------------------------------------
__global__ __launch_bounds__(256) void gather_seg(const int2* __restrict__ sorted,
    const int* __restrict__ totalK,
    const float* __restrict__ depth_ws, const float* __restrict__ img_ws,
    float* __restrict__ out) {
  int wid = (blockIdx.x << 2) + (threadIdx.x >> 6);
  int lane = threadIdx.x & 63;
  int K = *totalK;
  int start = wid * CHUNK;
  if (start >= K) return;
  int end = min(start + CHUNK, K);

  int2 s0 = sorted[start];
  int cur = s0.x;
  float acc = 0.f;
  for (int i = start; i < end; ++i) {
    int2 s = sorted[i];
    if (s.x != cur) {                     // wave-uniform branch
      int b = cur >> 14, vox = cur & 16383;
      unsafeAtomicAdd(&out[((size_t)((b << 6) + lane) << 14) + vox], acc);
      acc = 0.f;
      cur = s.x;
    }
    float dep = depth_ws[s.y];                          // broadcast load
    float im  = img_ws[(s.y & 0x7FFFFFC0) + lane];      // coalesced 256B
    acc += dep * im;
  }
  int b = cur >> 14, vox = cur & 16383;
  unsafeAtomicAdd(&out[((size_t)((b << 6) + lane) << 14) + vox], acc);
}

// ---------------------------------------------------------------------------
extern "C" void kernel_launch(void* const* d_in, const int* in_sizes, int n_in,
                              void* d_out, int out_size, void* d_ws, size_t ws_size,
                              hipStream_t stream) {
  const float* x    = (const float*)d_in[0];
  const float* rots = (const float*)d_in[1];
  const float* trn  = (const float*)d_in[2];
  const float* intr = (const float*)d_in[3];
  const float* prot = (const float*)d_in[4];
  const float* ptra = (const float*)d_in[5];
  const float* Wd   = (const float*)d_in[6];
  const float* bd   = (const float*)d_in[7];
  float* out = (float*)d_out;
  float* ws  = (float*)d_ws;

  // Layout identical in extent to the validated round-6..10 footprint.
  float* mats     = ws;                                    // 1024 floats
  float* depth_ws = ws + 1024;                             // 1,081,344
  float* img_ws   = depth_ws + (size_t)MPIX*64;            // 1,081,344
  int*   hist     = (int*)(img_ws + (size_t)MPIX*64);      // 524,288 (16B-aligned)
  int*   blockSums= hist + NKEY;                           // 512
  int*   totalK   = blockSums + 512;                       // 4 (pad)
  int2*  pr       = (int2*)(totalK + 4);                   // 996,864 int2
  int2*  sorted   = pr + P_TOT;                            // 996,864 int2
  // Wh/Wl (512 KB) alias the head of hist's 2 MB: read only by gemm_fused,
  // which completes (stream order) before the hist memset below.
  u16*   Wh       = (u16*)hist;                            // 65,536 u16
  u16*   Wl       = Wh + 65536;                            // 65,536 u16

  prep_convw<<<257, 256, 0, stream>>>(rots, trn, intr, prot, ptra, mats, Wd, Wh, Wl);
  gemm_fused<<<MPIX/32, 256, 0, stream>>>(x, Wh, Wl, bd, depth_ws, img_ws);
  (void)hipMemsetAsync(hist, 0, NKEY * sizeof(int), stream);
  (void)hipMemsetAsync(d_out, 0, (size_t)out_size * sizeof(float), stream);
  geom_k<<<NIMG*NPIX/4, 256, 0, stream>>>(mats, pr, hist);
  scan1_k<<<SCAN_BLKS, 256, 0, stream>>>(hist, blockSums);
  scan2_k<<<1, 512, 0, stream>>>(blockSums, totalK);
  scan3_k<<<SCAN_BLKS, 256, 0, stream>>>(hist, blockSums);
  order_k<<<(P_TOT + 255)/256, 256, 0, stream>>>(pr, hist, sorted);
  gather_seg<<<(P_TOT/CHUNK + 3)/4, 256, 0, stream>>>(sorted, totalK, depth_ws, img_ws, out);
}

// Round 12
// 147.291 us; speedup vs baseline: 1.0132x; 1.0132x over previous
//
#include <hip/hip_runtime.h>

#define NPIX 704
#define NIMG 24
#define NB 4
#define NCAM 6
#define DB 59
#define CT 64
#define P_TOT (NIMG*NPIX*DB)   // 996864
#define NVOX 65536             // 4 batches * 128*128 (gz==0 only)
#define SLC 8                  // histogram slices (contention spreading)
#define NKEY (NVOX*SLC)        // 524288
#define CHUNK 64
#define SCAN_BLKS 512          // NKEY / 1024
#define MPIX (NIMG*NPIX)       // 16896

typedef unsigned short u16;
typedef __attribute__((ext_vector_type(8))) unsigned short u16x8;
typedef __attribute__((ext_vector_type(4))) __bf16 bf16x4;
typedef __attribute__((ext_vector_type(8))) __bf16 bf16x8;
typedef __attribute__((ext_vector_type(4))) float f32x4;

__device__ inline u16 f2bf(float f) {          // RN float->bf16
  unsigned u = __float_as_uint(f);
  u += 0x7FFFu + ((u >> 16) & 1u);
  return (u16)(u >> 16);
}
__device__ inline float bf2f(u16 s) {
  return __uint_as_float(((unsigned)s) << 16);
}

// ---------------------------------------------------------------------------
// Kernel 1: W -> bf16 hi/lo (blocks 0..255) + per-(b,n) matrix prep (block 256)
// ---------------------------------------------------------------------------
__device__ inline void inv3(const double a[9], double o[9]) {
  double c0 = a[4]*a[8] - a[5]*a[7];
  double c1 = a[3]*a[8] - a[5]*a[6];
  double c2 = a[3]*a[7] - a[4]*a[6];
  double det = a[0]*c0 - a[1]*c1 + a[2]*c2;
  double id = 1.0 / det;
  o[0] =  c0 * id;
  o[1] = (a[2]*a[7] - a[1]*a[8]) * id;
  o[2] = (a[1]*a[5] - a[2]*a[4]) * id;
  o[3] = -c1 * id;
  o[4] = (a[0]*a[8] - a[2]*a[6]) * id;
  o[5] = (a[2]*a[3] - a[0]*a[5]) * id;
  o[6] =  c2 * id;
  o[7] = (a[1]*a[6] - a[0]*a[7]) * id;
  o[8] = (a[0]*a[4] - a[1]*a[3]) * id;
}

__global__ __launch_bounds__(256) void prep_convw(
    const float* __restrict__ rots, const float* __restrict__ trans,
    const float* __restrict__ intr, const float* __restrict__ prot,
    const float* __restrict__ ptra, float* __restrict__ mats,
    const float* __restrict__ Wd, u16* __restrict__ Wh, u16* __restrict__ Wl) {
  if (blockIdx.x < 256) {
    int idx = blockIdx.x * 256 + threadIdx.x;   // 128*512 entries, idx = o*512+k
    int o = idx >> 9;
    float f = (o < 123) ? Wd[idx] : 0.f;
    u16 h = f2bf(f);
    Wh[idx] = h;
    Wl[idx] = f2bf(f - bf2f(h));
    return;
  }
  int bn = threadIdx.x;
  if (bn >= NIMG) return;
  double pr[9], ik[9];
  for (int i = 0; i < 9; i++) { pr[i] = prot[bn*9 + i]; ik[i] = intr[bn*9 + i]; }
  double Minv[9], Kinv[9];
  inv3(pr, Minv);
  inv3(ik, Kinv);
  float* m = mats + bn*24;
  for (int i = 0; i < 9; i++) m[i] = (float)Minv[i];
  float kf[9];
  for (int i = 0; i < 9; i++) kf[i] = (float)Kinv[i];
  {
#pragma clang fp contract(off)
    for (int i = 0; i < 3; i++)
      for (int j = 0; j < 3; j++) {
        float s = rots[bn*9 + i*3 + 0] * kf[0*3 + j];
        s = s + rots[bn*9 + i*3 + 1] * kf[1*3 + j];
        s = s + rots[bn*9 + i*3 + 2] * kf[2*3 + j];
        m[9 + i*3 + j] = s;
      }
  }
  m[18] = ptra[bn*3 + 0]; m[19] = ptra[bn*3 + 1]; m[20] = ptra[bn*3 + 2];
  m[21] = trans[bn*3 + 0]; m[22] = trans[bn*3 + 1]; m[23] = trans[bn*3 + 2];
}

// ---------------------------------------------------------------------------
// Kernel 2: fused MFMA GEMM (bf16 hi/lo 3-term ~= fp32) + softmax.
// Tile 32 pix x 128 o x K=512, BK=64; 528 blocks, 4 waves.
// Software-pipelined: K-step kb+64's global loads issue into registers
// BEFORE computing kb; cvt + LDS write after the post-compute barrier.
// LDS: padded 144B rows (<=2-way banks), no xor. 46080 B.
// ---------------------------------------------------------------------------
__global__ __launch_bounds__(256) void gemm_fused(const float* __restrict__ x,
    const u16* __restrict__ Wh, const u16* __restrict__ Wl,
    const float* __restrict__ bd,
    float* __restrict__ depth_ws, float* __restrict__ img_ws) {
  __shared__ __attribute__((aligned(16))) unsigned char smem[46080];
  int t = threadIdx.x;
  int l = t & 63, wid = t >> 6;
  int wr = wid >> 1, wc = wid & 1;
  int pixbase = blockIdx.x << 5;       // 704 = 22*32: tile stays in one image
  int bn = pixbase / NPIX;
  int pix0 = pixbase - bn * NPIX;
  const float* xb = x + (size_t)bn * 512 * NPIX + pix0;

  // Per-thread staging coords
  int a_c0   = (t & 15) << 2;          // 0..60 (c quad)
  int a_pixt = (t >> 4) << 1;          // 0..30 (pix pair)
  int b_o    = t & 127;
  int b_kh   = (t >> 7) << 5;          // 0 or 32
  const u16* wh_row = Wh + (size_t)b_o * 512 + b_kh;
  const u16* wl_row = Wl + (size_t)b_o * 512 + b_kh;

  // Prefetch registers
  float2 pa[4];
  u16x8 pbh[4], pbl[4];

#define LOADK(KB)                                                              \
  {                                                                            \
    pa[0] = *(const float2*)&xb[(size_t)((KB) + a_c0 + 0) * NPIX + a_pixt];    \
    pa[1] = *(const float2*)&xb[(size_t)((KB) + a_c0 + 1) * NPIX + a_pixt];    \
    pa[2] = *(const float2*)&xb[(size_t)((KB) + a_c0 + 2) * NPIX + a_pixt];    \
    pa[3] = *(const float2*)&xb[(size_t)((KB) + a_c0 + 3) * NPIX + a_pixt];    \
    _Pragma("unroll")                                                          \
    for (int i = 0; i < 4; ++i) {                                              \
      pbh[i] = *(const u16x8*)(wh_row + (KB) + (i << 3));                      \
      pbl[i] = *(const u16x8*)(wl_row + (KB) + (i << 3));                      \
    }                                                                          \
  }

#define WRITEK()                                                               \
  {                                                                            \
    _Pragma("unroll")                                                          \
    for (int j = 0; j < 2; ++j) {                                              \
      float f0 = j ? pa[0].y : pa[0].x;                                        \
      float f1 = j ? pa[1].y : pa[1].x;                                        \
      float f2 = j ? pa[2].y : pa[2].x;                                        \
      float f3 = j ? pa[3].y : pa[3].x;                                        \
      __bf16 h0 = (__bf16)f0, h1 = (__bf16)f1, h2 = (__bf16)f2, h3 = (__bf16)f3;\
      bf16x4 hv = {h0, h1, h2, h3};                                            \
      bf16x4 lv = {(__bf16)(f0 - (float)h0), (__bf16)(f1 - (float)h1),         \
                   (__bf16)(f2 - (float)h2), (__bf16)(f3 - (float)h3)};        \
      int row = a_pixt + j;                                                    \
      *(bf16x4*)(smem + row * 144 + a_c0 * 2) = hv;                            \
      *(bf16x4*)(smem + 4608 + row * 144 + a_c0 * 2) = lv;                     \
    }                                                                          \
    _Pragma("unroll")                                                          \
    for (int i = 0; i < 4; ++i) {                                              \
      int kkb = (b_kh + (i << 3)) * 2;                                         \
      *(u16x8*)(smem + 9216 + b_o * 144 + kkb) = pbh[i];                       \
      *(u16x8*)(smem + 27648 + b_o * 144 + kkb) = pbl[i];                      \
    }                                                                          \
  }

  f32x4 zero4 = {0.f, 0.f, 0.f, 0.f};
  f32x4 acc[4];
#pragma unroll
  for (int ni = 0; ni < 4; ni++) acc[ni] = zero4;

  // Prologue: stage kb=0
  LOADK(0);
  WRITEK();
  __syncthreads();

  for (int kb = 0; kb < 512; kb += 64) {
    if (kb + 64 < 512) LOADK(kb + 64);   // issue next-tile loads early
    // ---- compute current tile: 2 k-halves x 4 frags x 3 MFMA ----
#pragma unroll
    for (int h = 0; h < 2; ++h) {
      int kk2 = (h * 32 + ((l >> 4) << 3)) * 2;     // byte offset in row
      int arow = (wr << 4) + (l & 15);
      bf16x8 ah = *(const bf16x8*)(smem + arow * 144 + kk2);
      bf16x8 al = *(const bf16x8*)(smem + 4608 + arow * 144 + kk2);
#pragma unroll
      for (int ni = 0; ni < 4; ++ni) {
        int o = (wc << 6) + (ni << 4) + (l & 15);
        bf16x8 bh_ = *(const bf16x8*)(smem + 9216 + o * 144 + kk2);
        bf16x8 bl_ = *(const bf16x8*)(smem + 27648 + o * 144 + kk2);
        acc[ni] = __builtin_amdgcn_mfma_f32_16x16x32_bf16(ah, bh_, acc[ni], 0, 0, 0);
        acc[ni] = __builtin_amdgcn_mfma_f32_16x16x32_bf16(ah, bl_, acc[ni], 0, 0, 0);
        acc[ni] = __builtin_amdgcn_mfma_f32_16x16x32_bf16(al, bh_, acc[ni], 0, 0, 0);
      }
    }
    __syncthreads();                     // all waves done reading LDS
    if (kb + 64 < 512) {
      WRITEK();                          // vmcnt-wait lands here, after compute
      __syncthreads();
    }
  }

  // ---- epilogue: acc -> F[32][132], then wave softmax ----
  float* F = (float*)smem;
#pragma unroll
  for (int ni = 0; ni < 4; ++ni)
#pragma unroll
    for (int r = 0; r < 4; ++r) {
      int row = (wr << 4) + ((l >> 4) << 2) + r;
      int col = (wc << 6) + (ni << 4) + (l & 15);
      F[row * 132 + col] = acc[ni][r];
    }
  __syncthreads();

  int c = l;
  float bA = bd[c];
  float bI = bd[DB + c];
  for (int p = wid; p < 32; p += 4) {
    float fA = F[p * 132 + c] + bA;
    float fI = F[p * 132 + DB + c] + bI;
    float mv = (c < DB) ? fA : -3.4e38f;
#pragma unroll
    for (int ofs = 32; ofs > 0; ofs >>= 1) mv = fmaxf(mv, __shfl_xor(mv, ofs));
    float ev = (c < DB) ? expf(fA - mv) : 0.f;
    float sv = ev;
#pragma unroll
    for (int ofs = 32; ofs > 0; ofs >>= 1) sv += __shfl_xor(sv, ofs);
    size_t rec = (size_t)(pixbase + p) << 6;
    if (c < DB) depth_ws[rec + c] = ev / sv;
    img_ws[rec + c] = fI;
  }
#undef LOADK
#undef WRITEK
}

// ---------------------------------------------------------------------------
// Kernel 3: geometry -> sliced key + rank via hist atomic.
// ---------------------------------------------------------------------------
__global__ __launch_bounds__(256) void geom_k(const float* __restrict__ mats,
    int2* __restrict__ pr, int* __restrict__ hist) {
  int wid = (blockIdx.x << 2) + (threadIdx.x >> 6);
  int lane = threadIdx.x & 63;
  int bn = wid / NPIX;
  int pix = wid - bn*NPIX;
  int b = bn / NCAM;
  int h = pix / 44, w = pix - h*44;
  const float* M = mats + bn*24;

  int code = -1;
  {
#pragma clang fp contract(off)
    float xs = (float)((double)w * (703.0 / 43.0));
    float ys = (float)(h * 17);
    float dval = (float)(lane + 1);
    float vx = xs - M[18], vy = ys - M[19], vz = dval - M[20];
    float qx = M[0]*vx + M[1]*vy + M[2]*vz;
    float qy = M[3]*vx + M[4]*vy + M[5]*vz;
    float qz = M[6]*vx + M[7]*vy + M[8]*vz;
    float rx = qx*qz, ry = qy*qz;
    float px = M[9]*rx  + M[10]*ry + M[11]*qz + M[21];
    float py = M[12]*rx + M[13]*ry + M[14]*qz + M[22];
    float pz = M[15]*rx + M[16]*ry + M[17]*qz + M[23];
    float gx = floorf((px - (-50.8f - 0.4f)) / 0.8f);
    float gy = floorf((py - (-50.8f - 0.4f)) / 0.8f);
    float gz = floorf((pz - (0.0f - 10.0f)) / 20.0f);
    bool kept = (lane < DB) && (gx >= 0.f) && (gx < 128.f) &&
                (gy >= 0.f) && (gy < 128.f) && (gz == 0.f);
    if (kept) code = (b << 14) + (int)gy * 128 + (int)gx;
  }

  if (lane < DB) {
    int key = -1, r = 0;
    if (code >= 0) {
      key = code * SLC + ((wid + lane) & (SLC - 1));
      r = atomicAdd(&hist[key], 1);
    }
    pr[(size_t)wid * DB + lane] = make_int2(key, r);
  }
}

// ---------------------------------------------------------------------------
// Kernels 4a/4b/4c: hierarchical exclusive scan of hist[NKEY].
// ---------------------------------------------------------------------------
__global__ __launch_bounds__(256) void scan1_k(const int* __restrict__ hist,
    int* __restrict__ blockSums) {
  __shared__ int red[256];
  int t = threadIdx.x;
  const int4* h4 = (const int4*)(hist + (blockIdx.x << 10));
  int4 v = h4[t];
  red[t] = v.x + v.y + v.z + v.w;
  __syncthreads();
  for (int ofs = 128; ofs > 0; ofs >>= 1) {
    if (t < ofs) red[t] += red[t + ofs];
    __syncthreads();
  }
  if (t == 0) blockSums[blockIdx.x] = red[0];
}

__global__ __launch_bounds__(512) void scan2_k(int* __restrict__ blockSums,
    int* __restrict__ totalK) {
  __shared__ int buf[2][512];
  int t = threadIdx.x;
  buf[0][t] = blockSums[t];
  __syncthreads();
  int src = 0;
  for (int ofs = 1; ofs < 512; ofs <<= 1) {
    int v = buf[src][t];
    if (t >= ofs) v += buf[src][t - ofs];
    buf[src ^ 1][t] = v;
    __syncthreads();
    src ^= 1;
  }
  blockSums[t] = (t == 0) ? 0 : buf[src][t - 1];
  if (t == 511) *totalK = buf[src][511];
}

__global__ __launch_bounds__(256) void scan3_k(int* __restrict__ hist,
    const int* __restrict__ blockSums) {
  __shared__ int buf[2][256];
  int t = threadIdx.x;
  int4* h4 = (int4*)(hist + (blockIdx.x << 10));
  int4 v = h4[t];
  int s = v.x + v.y + v.z + v.w;
  buf[0][t] = s;
  __syncthreads();
  int src = 0;
  for (int ofs = 1; ofs < 256; ofs <<= 1) {
    int vv = buf[src][t];
    if (t >= ofs) vv += buf[src][t - ofs];
    buf[src ^ 1][t] = vv;
    __syncthreads();
    src ^= 1;
  }
  int run = blockSums[blockIdx.x] + ((t == 0) ? 0 : buf[src][t - 1]);
  int4 o;
  o.x = run; run += v.x;
  o.y = run; run += v.y;
  o.z = run; run += v.z;
  o.w = run;
  h4[t] = o;
}

// ---------------------------------------------------------------------------
// Kernel 5: atomic-free placement: pos = offsets[key] + rank.
// ---------------------------------------------------------------------------
__global__ __launch_bounds__(256) void order_k(const int2* __restrict__ pr,
    const int* __restrict__ offsets, int2* __restrict__ sorted) {
  int p = blockIdx.x * 256 + threadIdx.x;
  if (p >= P_TOT) return;
  int2 e = pr[p];
  if (e.x >= 0) {
    int pos = offsets[e.x] + e.y;
    int bnpix = p / DB;
    int d = p - bnpix * DB;
    sorted[pos] = make_int2(e.x / SLC, (bnpix << 6) + d);
  }
}

// ---------------------------------------------------------------------------
// Kernel 6: segmented gather. One wave per CHUNK sorted points; lane = channel.
// ---------------------------------------------------------------------------
__global__ __launch_bounds__(256) void gather_seg(const int2* __restrict__ sorted,
    const int* __restrict__ totalK,
    const float* __restrict__ depth_ws, const float* __restrict__ img_ws,
    float* __restrict__ out) {
  int wid = (blockIdx.x << 2) + (threadIdx.x >> 6);
  int lane = threadIdx.x & 63;
  int K = *totalK;
  int start = wid * CHUNK;
  if (start >= K) return;
  int end = min(start + CHUNK, K);

  int2 s0 = sorted[start];
  int cur = s0.x;
  float acc = 0.f;
  for (int i = start; i < end; ++i) {
    int2 s = sorted[i];
    if (s.x != cur) {                     // wave-uniform branch
      int b = cur >> 14, vox = cur & 16383;
      unsafeAtomicAdd(&out[((size_t)((b << 6) + lane) << 14) + vox], acc);
      acc = 0.f;
      cur = s.x;
    }
    float dep = depth_ws[s.y];                          // broadcast load
    float im  = img_ws[(s.y & 0x7FFFFFC0) + lane];      // coalesced 256B
    acc += dep * im;
  }
  int b = cur >> 14, vox = cur & 16383;
  unsafeAtomicAdd(&out[((size_t)((b << 6) + lane) << 14) + vox], acc);
}

// ---------------------------------------------------------------------------
extern "C" void kernel_launch(void* const* d_in, const int* in_sizes, int n_in,
                              void* d_out, int out_size, void* d_ws, size_t ws_size,
                              hipStream_t stream) {
  const float* x    = (const float*)d_in[0];
  const float* rots = (const float*)d_in[1];
  const float* trn  = (const float*)d_in[2];
  const float* intr = (const float*)d_in[3];
  const float* prot = (const float*)d_in[4];
  const float* ptra = (const float*)d_in[5];
  const float* Wd   = (const float*)d_in[6];
  const float* bd   = (const float*)d_in[7];
  float* out = (float*)d_out;
  float* ws  = (float*)d_ws;

  // Layout identical in extent to the validated round-6..11 footprint.
  float* mats     = ws;                                    // 1024 floats
  float* depth_ws = ws + 1024;                             // 1,081,344
  float* img_ws   = depth_ws + (size_t)MPIX*64;            // 1,081,344
  int*   hist     = (int*)(img_ws + (size_t)MPIX*64);      // 524,288 (16B-aligned)
  int*   blockSums= hist + NKEY;                           // 512
  int*   totalK   = blockSums + 512;                       // 4 (pad)
  int2*  pr       = (int2*)(totalK + 4);                   // 996,864 int2
  int2*  sorted   = pr + P_TOT;                            // 996,864 int2
  // Wh/Wl (512 KB) alias the head of hist's 2 MB: read only by gemm_fused,
  // which completes (stream order) before the hist memset below.
  u16*   Wh       = (u16*)hist;                            // 65,536 u16
  u16*   Wl       = Wh + 65536;                            // 65,536 u16

  prep_convw<<<257, 256, 0, stream>>>(rots, trn, intr, prot, ptra, mats, Wd, Wh, Wl);
  gemm_fused<<<MPIX/32, 256, 0, stream>>>(x, Wh, Wl, bd, depth_ws, img_ws);
  (void)hipMemsetAsync(hist, 0, NKEY * sizeof(int), stream);
  (void)hipMemsetAsync(d_out, 0, (size_t)out_size * sizeof(float), stream);
  geom_k<<<NIMG*NPIX/4, 256, 0, stream>>>(mats, pr, hist);
  scan1_k<<<SCAN_BLKS, 256, 0, stream>>>(hist, blockSums);
  scan2_k<<<1, 512, 0, stream>>>(blockSums, totalK);
  scan3_k<<<SCAN_BLKS, 256, 0, stream>>>(hist, blockSums);
  order_k<<<(P_TOT + 255)/256, 256, 0, stream>>>(pr, hist, sorted);
  gather_seg<<<(P_TOT/CHUNK + 3)/4, 256, 0, stream>>>(sorted, totalK, depth_ws, img_ws, out);
}

// Round 14
// 133.183 us; speedup vs baseline: 1.1205x; 1.1059x over previous
//
#include <hip/hip_runtime.h>

#define NPIX 704
#define NIMG 24
#define NB 4
#define NCAM 6
#define DB 59
#define CT 64
#define P_TOT (NIMG*NPIX*DB)   // 996864
#define NVOX 65536             // 4 batches * 128*128 (gz==0 only)
#define SLC 8                  // histogram slices (contention spreading)
#define NKEY (NVOX*SLC)        // 524288
#define CHUNK 64
#define SCAN_BLKS 512          // NKEY / 1024
#define MPIX (NIMG*NPIX)       // 16896

typedef unsigned short u16;
typedef __attribute__((ext_vector_type(8))) unsigned short u16x8;
typedef __attribute__((ext_vector_type(4))) __bf16 bf16x4;
typedef __attribute__((ext_vector_type(8))) __bf16 bf16x8;
typedef __attribute__((ext_vector_type(4))) float f32x4;

__device__ inline u16 f2bf(float f) {          // RN float->bf16
  unsigned u = __float_as_uint(f);
  u += 0x7FFFu + ((u >> 16) & 1u);
  return (u16)(u >> 16);
}
__device__ inline float bf2f(u16 s) {
  return __uint_as_float(((unsigned)s) << 16);
}

// ---------------------------------------------------------------------------
// Kernel 1: pack W (bf16 hi/lo) into STAGING order (blocks 0..255) +
// per-(b,n) matrix prep (block 256).
// Staging layout: flat = ((kb6*8 + half*4 + i)*128 + o)*8 + j holds
//   W[o][k = kb6*64 + half*32 + i*8 + j]
// so gemm's B-staging load i for thread t (o = t&127, half = t>>7) is one
// 16B/lane fully-coalesced read. Data loaded is IDENTICAL to r12's
// Wh[o*512 + kb + kh + i*8 + j] — only the address pattern changes.
// ---------------------------------------------------------------------------
__device__ inline void inv3(const double a[9], double o[9]) {
  double c0 = a[4]*a[8] - a[5]*a[7];
  double c1 = a[3]*a[8] - a[5]*a[6];
  double c2 = a[3]*a[7] - a[4]*a[6];
  double det = a[0]*c0 - a[1]*c1 + a[2]*c2;
  double id = 1.0 / det;
  o[0] =  c0 * id;
  o[1] = (a[2]*a[7] - a[1]*a[8]) * id;
  o[2] = (a[1]*a[5] - a[2]*a[4]) * id;
  o[3] = -c1 * id;
  o[4] = (a[0]*a[8] - a[2]*a[6]) * id;
  o[5] = (a[2]*a[3] - a[0]*a[5]) * id;
  o[6] =  c2 * id;
  o[7] = (a[1]*a[6] - a[0]*a[7]) * id;
  o[8] = (a[0]*a[4] - a[1]*a[3]) * id;
}

__global__ __launch_bounds__(256) void prep_convw(
    const float* __restrict__ rots, const float* __restrict__ trans,
    const float* __restrict__ intr, const float* __restrict__ prot,
    const float* __restrict__ ptra, float* __restrict__ mats,
    const float* __restrict__ Wd, u16* __restrict__ PBh, u16* __restrict__ PBl) {
  if (blockIdx.x < 256) {
    int flat = blockIdx.x * 256 + threadIdx.x;   // 65536 entries
    int j    = flat & 7;
    int o    = (flat >> 3) & 127;
    int i    = (flat >> 10) & 3;
    int half = (flat >> 12) & 1;
    int kb6  = flat >> 13;                       // 0..7
    int k    = kb6 * 64 + half * 32 + i * 8 + j; // 0..511
    float f  = (o < 123) ? Wd[o * 512 + k] : 0.f;
    u16 h = f2bf(f);
    PBh[flat] = h;
    PBl[flat] = f2bf(f - bf2f(h));
    return;
  }
  int bn = threadIdx.x;
  if (bn >= NIMG) return;
  double pr[9], ik[9];
  for (int i = 0; i < 9; i++) { pr[i] = prot[bn*9 + i]; ik[i] = intr[bn*9 + i]; }
  double Minv[9], Kinv[9];
  inv3(pr, Minv);
  inv3(ik, Kinv);
  float* m = mats + bn*24;
  for (int i = 0; i < 9; i++) m[i] = (float)Minv[i];
  float kf[9];
  for (int i = 0; i < 9; i++) kf[i] = (float)Kinv[i];
  {
#pragma clang fp contract(off)
    for (int i = 0; i < 3; i++)
      for (int j = 0; j < 3; j++) {
        float s = rots[bn*9 + i*3 + 0] * kf[0*3 + j];
        s = s + rots[bn*9 + i*3 + 1] * kf[1*3 + j];
        s = s + rots[bn*9 + i*3 + 2] * kf[2*3 + j];
        m[9 + i*3 + j] = s;
      }
  }
  m[18] = ptra[bn*3 + 0]; m[19] = ptra[bn*3 + 1]; m[20] = ptra[bn*3 + 2];
  m[21] = trans[bn*3 + 0]; m[22] = trans[bn*3 + 1]; m[23] = trans[bn*3 + 2];
}

// ---------------------------------------------------------------------------
// Kernel 2: fused MFMA GEMM (bf16 hi/lo 3-term ~= fp32) + softmax.
// Identical to the round-12 PASSING kernel except the B global loads come
// from the staging-packed arrays (coalesced 16B/lane). LDS contents, frag
// reads, MFMA sequence, epilogue: bit-identical to r12.
// ---------------------------------------------------------------------------
__global__ __launch_bounds__(256) void gemm_fused(const float* __restrict__ x,
    const u16* __restrict__ PBh, const u16* __restrict__ PBl,
    const float* __restrict__ bd,
    float* __restrict__ depth_ws, float* __restrict__ img_ws) {
  __shared__ __attribute__((aligned(16))) unsigned char smem[46080];
  int t = threadIdx.x;
  int l = t & 63, wid = t >> 6;
  int wr = wid >> 1, wc = wid & 1;
  int pixbase = blockIdx.x << 5;       // 704 = 22*32: tile stays in one image
  int bn = pixbase / NPIX;
  int pix0 = pixbase - bn * NPIX;
  const float* xb = x + (size_t)bn * 512 * NPIX + pix0;

  // Per-thread staging coords
  int a_c0   = (t & 15) << 2;          // 0..60 (c quad)
  int a_pixt = (t >> 4) << 1;          // 0..30 (pix pair)
  int b_o    = t & 127;
  int b_kh   = (t >> 7) << 5;          // 0 or 32

  // Prefetch registers
  float2 pa[4];
  u16x8 pbh[4], pbl[4];

#define LOADK(KB)                                                              \
  {                                                                            \
    pa[0] = *(const float2*)&xb[(size_t)((KB) + a_c0 + 0) * NPIX + a_pixt];    \
    pa[1] = *(const float2*)&xb[(size_t)((KB) + a_c0 + 1) * NPIX + a_pixt];    \
    pa[2] = *(const float2*)&xb[(size_t)((KB) + a_c0 + 2) * NPIX + a_pixt];    \
    pa[3] = *(const float2*)&xb[(size_t)((KB) + a_c0 + 3) * NPIX + a_pixt];    \
    size_t gb = ((((size_t)((KB) >> 6) << 3) + ((size_t)(t >> 7) << 2)) << 10) \
                + ((size_t)(t & 127) << 3);                                    \
    _Pragma("unroll")                                                          \
    for (int i = 0; i < 4; ++i) {                                              \
      pbh[i] = *(const u16x8*)(PBh + gb + ((size_t)i << 10));                  \
      pbl[i] = *(const u16x8*)(PBl + gb + ((size_t)i << 10));                  \
    }                                                                          \
  }

#define WRITEK()                                                               \
  {                                                                            \
    _Pragma("unroll")                                                          \
    for (int j = 0; j < 2; ++j) {                                              \
      float f0 = j ? pa[0].y : pa[0].x;                                        \
      float f1 = j ? pa[1].y : pa[1].x;                                        \
      float f2 = j ? pa[2].y : pa[2].x;                                        \
      float f3 = j ? pa[3].y : pa[3].x;                                        \
      __bf16 h0 = (__bf16)f0, h1 = (__bf16)f1, h2 = (__bf16)f2, h3 = (__bf16)f3;\
      bf16x4 hv = {h0, h1, h2, h3};                                            \
      bf16x4 lv = {(__bf16)(f0 - (float)h0), (__bf16)(f1 - (float)h1),         \
                   (__bf16)(f2 - (float)h2), (__bf16)(f3 - (float)h3)};        \
      int row = a_pixt + j;                                                    \
      *(bf16x4*)(smem + row * 144 + a_c0 * 2) = hv;                            \
      *(bf16x4*)(smem + 4608 + row * 144 + a_c0 * 2) = lv;                     \
    }                                                                          \
    _Pragma("unroll")                                                          \
    for (int i = 0; i < 4; ++i) {                                              \
      int kkb = (b_kh + (i << 3)) * 2;                                         \
      *(u16x8*)(smem + 9216 + b_o * 144 + kkb) = pbh[i];                       \
      *(u16x8*)(smem + 27648 + b_o * 144 + kkb) = pbl[i];                      \
    }                                                                          \
  }

  f32x4 zero4 = {0.f, 0.f, 0.f, 0.f};
  f32x4 acc[4];
#pragma unroll
  for (int ni = 0; ni < 4; ni++) acc[ni] = zero4;

  // Prologue: stage kb=0
  LOADK(0);
  WRITEK();
  __syncthreads();

  for (int kb = 0; kb < 512; kb += 64) {
    if (kb + 64 < 512) LOADK(kb + 64);   // issue next-tile loads early
    // ---- compute current tile: 2 k-halves x 4 frags x 3 MFMA ----
#pragma unroll
    for (int h = 0; h < 2; ++h) {
      int kk2 = (h * 32 + ((l >> 4) << 3)) * 2;     // byte offset in row
      int arow = (wr << 4) + (l & 15);
      bf16x8 ah = *(const bf16x8*)(smem + arow * 144 + kk2);
      bf16x8 al = *(const bf16x8*)(smem + 4608 + arow * 144 + kk2);
#pragma unroll
      for (int ni = 0; ni < 4; ++ni) {
        int o = (wc << 6) + (ni << 4) + (l & 15);
        bf16x8 bh_ = *(const bf16x8*)(smem + 9216 + o * 144 + kk2);
        bf16x8 bl_ = *(const bf16x8*)(smem + 27648 + o * 144 + kk2);
        acc[ni] = __builtin_amdgcn_mfma_f32_16x16x32_bf16(ah, bh_, acc[ni], 0, 0, 0);
        acc[ni] = __builtin_amdgcn_mfma_f32_16x16x32_bf16(ah, bl_, acc[ni], 0, 0, 0);
        acc[ni] = __builtin_amdgcn_mfma_f32_16x16x32_bf16(al, bh_, acc[ni], 0, 0, 0);
      }
    }
    __syncthreads();                     // all waves done reading LDS
    if (kb + 64 < 512) {
      WRITEK();                          // vmcnt-wait lands here, after compute
      __syncthreads();
    }
  }

  // ---- epilogue: acc -> F[32][132], then wave softmax ----
  float* F = (float*)smem;
#pragma unroll
  for (int ni = 0; ni < 4; ++ni)
#pragma unroll
    for (int r = 0; r < 4; ++r) {
      int row = (wr << 4) + ((l >> 4) << 2) + r;
      int col = (wc << 6) + (ni << 4) + (l & 15);
      F[row * 132 + col] = acc[ni][r];
    }
  __syncthreads();

  int c = l;
  float bA = bd[c];
  float bI = bd[DB + c];
  for (int p = wid; p < 32; p += 4) {
    float fA = F[p * 132 + c] + bA;
    float fI = F[p * 132 + DB + c] + bI;
    float mv = (c < DB) ? fA : -3.4e38f;
#pragma unroll
    for (int ofs = 32; ofs > 0; ofs >>= 1) mv = fmaxf(mv, __shfl_xor(mv, ofs));
    float ev = (c < DB) ? expf(fA - mv) : 0.f;
    float sv = ev;
#pragma unroll
    for (int ofs = 32; ofs > 0; ofs >>= 1) sv += __shfl_xor(sv, ofs);
    size_t rec = (size_t)(pixbase + p) << 6;
    if (c < DB) depth_ws[rec + c] = ev / sv;
    img_ws[rec + c] = fI;
  }
#undef LOADK
#undef WRITEK
}

// ---------------------------------------------------------------------------
// Kernel 3: geometry -> sliced key + rank via hist atomic.
// ---------------------------------------------------------------------------
__global__ __launch_bounds__(256) void geom_k(const float* __restrict__ mats,
    int2* __restrict__ pr, int* __restrict__ hist) {
  int wid = (blockIdx.x << 2) + (threadIdx.x >> 6);
  int lane = threadIdx.x & 63;
  int bn = wid / NPIX;
  int pix = wid - bn*NPIX;
  int b = bn / NCAM;
  int h = pix / 44, w = pix - h*44;
  const float* M = mats + bn*24;

  int code = -1;
  {
#pragma clang fp contract(off)
    float xs = (float)((double)w * (703.0 / 43.0));
    float ys = (float)(h * 17);
    float dval = (float)(lane + 1);
    float vx = xs - M[18], vy = ys - M[19], vz = dval - M[20];
    float qx = M[0]*vx + M[1]*vy + M[2]*vz;
    float qy = M[3]*vx + M[4]*vy + M[5]*vz;
    float qz = M[6]*vx + M[7]*vy + M[8]*vz;
    float rx = qx*qz, ry = qy*qz;
    float px = M[9]*rx  + M[10]*ry + M[11]*qz + M[21];
    float py = M[12]*rx + M[13]*ry + M[14]*qz + M[22];
    float pz = M[15]*rx + M[16]*ry + M[17]*qz + M[23];
    float gx = floorf((px - (-50.8f - 0.4f)) / 0.8f);
    float gy = floorf((py - (-50.8f - 0.4f)) / 0.8f);
    float gz = floorf((pz - (0.0f - 10.0f)) / 20.0f);
    bool kept = (lane < DB) && (gx >= 0.f) && (gx < 128.f) &&
                (gy >= 0.f) && (gy < 128.f) && (gz == 0.f);
    if (kept) code = (b << 14) + (int)gy * 128 + (int)gx;
  }

  if (lane < DB) {
    int key = -1, r = 0;
    if (code >= 0) {
      key = code * SLC + ((wid + lane) & (SLC - 1));
      r = atomicAdd(&hist[key], 1);
    }
    pr[(size_t)wid * DB + lane] = make_int2(key, r);
  }
}

// ---------------------------------------------------------------------------
// Kernels 4a/4b/4c: hierarchical exclusive scan of hist[NKEY].
// ---------------------------------------------------------------------------
__global__ __launch_bounds__(256) void scan1_k(const int* __restrict__ hist,
    int* __restrict__ blockSums) {
  __shared__ int red[256];
  int t = threadIdx.x;
  const int4* h4 = (const int4*)(hist + (blockIdx.x << 10));
  int4 v = h4[t];
  red[t] = v.x + v.y + v.z + v.w;
  __syncthreads();
  for (int ofs = 128; ofs > 0; ofs >>= 1) {
    if (t < ofs) red[t] += red[t + ofs];
    __syncthreads();
  }
  if (t == 0) blockSums[blockIdx.x] = red[0];
}

__global__ __launch_bounds__(512) void scan2_k(int* __restrict__ blockSums,
    int* __restrict__ totalK) {
  __shared__ int buf[2][512];
  int t = threadIdx.x;
  buf[0][t] = blockSums[t];
  __syncthreads();
  int src = 0;
  for (int ofs = 1; ofs < 512; ofs <<= 1) {
    int v = buf[src][t];
    if (t >= ofs) v += buf[src][t - ofs];
    buf[src ^ 1][t] = v;
    __syncthreads();
    src ^= 1;
  }
  blockSums[t] = (t == 0) ? 0 : buf[src][t - 1];
  if (t == 511) *totalK = buf[src][511];
}

__global__ __launch_bounds__(256) void scan3_k(int* __restrict__ hist,
    const int* __restrict__ blockSums) {
  __shared__ int buf[2][256];
  int t = threadIdx.x;
  int4* h4 = (int4*)(hist + (blockIdx.x << 10));
  int4 v = h4[t];
  int s = v.x + v.y + v.z + v.w;
  buf[0][t] = s;
  __syncthreads();
  int src = 0;
  for (int ofs = 1; ofs < 256; ofs <<= 1) {
    int vv = buf[src][t];
    if (t >= ofs) vv += buf[src][t - ofs];
    buf[src ^ 1][t] = vv;
    __syncthreads();
    src ^= 1;
  }
  int run = blockSums[blockIdx.x] + ((t == 0) ? 0 : buf[src][t - 1]);
  int4 o;
  o.x = run; run += v.x;
  o.y = run; run += v.y;
  o.z = run; run += v.z;
  o.w = run;
  h4[t] = o;
}

// ---------------------------------------------------------------------------
// Kernel 5: atomic-free placement: pos = offsets[key] + rank.
// ---------------------------------------------------------------------------
__global__ __launch_bounds__(256) void order_k(const int2* __restrict__ pr,
    const int* __restrict__ offsets, int2* __restrict__ sorted) {
  int p = blockIdx.x * 256 + threadIdx.x;
  if (p >= P_TOT) return;
  int2 e = pr[p];
  if (e.x >= 0) {
    int pos = offsets[e.x] + e.y;
    int bnpix = p / DB;
    int d = p - bnpix * DB;
    sorted[pos] = make_int2(e.x / SLC, (bnpix << 6) + d);
  }
}

// ---------------------------------------------------------------------------
// Kernel 6: segmented gather. One wave per CHUNK sorted points; lane = channel.
// ---------------------------------------------------------------------------
__global__ __launch_bounds__(256) void gather_seg(const int2* __restrict__ sorted,
    const int* __restrict__ totalK,
    const float* __restrict__ depth_ws, const float* __restrict__ img_ws,
    float* __restrict__ out) {
  int wid = (blockIdx.x << 2) + (threadIdx.x >> 6);
  int lane = threadIdx.x & 63;
  int K = *totalK;
  int start = wid * CHUNK;
  if (start >= K) return;
  int end = min(start + CHUNK, K);

  int2 s0 = sorted[start];
  int cur = s0.x;
  float acc = 0.f;
  for (int i = start; i < end; ++i) {
    int2 s = sorted[i];
    if (s.x != cur) {                     // wave-uniform branch
      int b = cur >> 14, vox = cur & 16383;
      unsafeAtomicAdd(&out[((size_t)((b << 6) + lane) << 14) + vox], acc);
      acc = 0.f;
      cur = s.x;
    }
    float dep = depth_ws[s.y];                          // broadcast load
    float im  = img_ws[(s.y & 0x7FFFFFC0) + lane];      // coalesced 256B
    acc += dep * im;
  }
  int b = cur >> 14, vox = cur & 16383;
  unsafeAtomicAdd(&out[((size_t)((b << 6) + lane) << 14) + vox], acc);
}

// ---------------------------------------------------------------------------
extern "C" void kernel_launch(void* const* d_in, const int* in_sizes, int n_in,
                              void* d_out, int out_size, void* d_ws, size_t ws_size,
                              hipStream_t stream) {
  const float* x    = (const float*)d_in[0];
  const float* rots = (const float*)d_in[1];
  const float* trn  = (const float*)d_in[2];
  const float* intr = (const float*)d_in[3];
  const float* prot = (const float*)d_in[4];
  const float* ptra = (const float*)d_in[5];
  const float* Wd   = (const float*)d_in[6];
  const float* bd   = (const float*)d_in[7];
  float* out = (float*)d_out;
  float* ws  = (float*)d_ws;

  // Layout identical in extent to the validated round-6..12 footprint.
  float* mats     = ws;                                    // 1024 floats
  float* depth_ws = ws + 1024;                             // 1,081,344
  float* img_ws   = depth_ws + (size_t)MPIX*64;            // 1,081,344
  int*   hist     = (int*)(img_ws + (size_t)MPIX*64);      // 524,288 (16B-aligned)
  int*   blockSums= hist + NKEY;                           // 512
  int*   totalK   = blockSums + 512;                       // 4 (pad)
  int2*  pr       = (int2*)(totalK + 4);                   // 996,864 int2
  int2*  sorted   = pr + P_TOT;                            // 996,864 int2
  // Packed-W (256 KB) aliases the head of hist's 2 MB: read only by
  // gemm_fused, which completes (stream order) before the hist memset below.
  u16*   PBh      = (u16*)hist;                            // 65,536 u16
  u16*   PBl      = PBh + 65536;                           // 65,536 u16

  prep_convw<<<257, 256, 0, stream>>>(rots, trn, intr, prot, ptra, mats, Wd, PBh, PBl);
  gemm_fused<<<MPIX/32, 256, 0, stream>>>(x, PBh, PBl, bd, depth_ws, img_ws);
  (void)hipMemsetAsync(hist, 0, NKEY * sizeof(int), stream);
  (void)hipMemsetAsync(d_out, 0, (size_t)out_size * sizeof(float), stream);
  geom_k<<<NIMG*NPIX/4, 256, 0, stream>>>(mats, pr, hist);
  scan1_k<<<SCAN_BLKS, 256, 0, stream>>>(hist, blockSums);
  scan2_k<<<1, 512, 0, stream>>>(blockSums, totalK);
  scan3_k<<<SCAN_BLKS, 256, 0, stream>>>(hist, blockSums);
  order_k<<<(P_TOT + 255)/256, 256, 0, stream>>>(pr, hist, sorted);
  gather_seg<<<(P_TOT/CHUNK + 3)/4, 256, 0, stream>>>(sorted, totalK, depth_ws, img_ws, out);
}

// Round 15
// 129.310 us; speedup vs baseline: 1.1541x; 1.0300x over previous
//
#include <hip/hip_runtime.h>

#define NPIX 704
#define NIMG 24
#define NB 4
#define NCAM 6
#define DB 59
#define CT 64
#define P_TOT (NIMG*NPIX*DB)   // 996864
#define NVOX 65536             // 4 batches * 128*128 (gz==0 only)
#define SLC 8                  // histogram slices (contention spreading)
#define NKEY (NVOX*SLC)        // 524288
#define CHUNK 64
#define SCAN_BLKS 512          // NKEY / 1024
#define MPIX (NIMG*NPIX)       // 16896
#define OUT_F4 (NB*64*16384/4) // 1,048,576 float4 in d_out
#define HIST_F4 (NKEY/4)       // 131,072 float4 in hist

typedef unsigned short u16;
typedef __attribute__((ext_vector_type(8))) unsigned short u16x8;
typedef __attribute__((ext_vector_type(4))) __bf16 bf16x4;
typedef __attribute__((ext_vector_type(8))) __bf16 bf16x8;
typedef __attribute__((ext_vector_type(4))) float f32x4;

__device__ inline u16 f2bf(float f) {          // RN float->bf16
  unsigned u = __float_as_uint(f);
  u += 0x7FFFu + ((u >> 16) & 1u);
  return (u16)(u >> 16);
}
__device__ inline float bf2f(u16 s) {
  return __uint_as_float(((unsigned)s) << 16);
}

// ---------------------------------------------------------------------------
// Kernel 0: fast zero of d_out + hist (runtime fillBuffer was 390 GB/s).
// ---------------------------------------------------------------------------
__global__ __launch_bounds__(256) void zero_ws(float4* __restrict__ out4,
                                               float4* __restrict__ hist4) {
  int i = blockIdx.x * 256 + threadIdx.x;
  float4 z = make_float4(0.f, 0.f, 0.f, 0.f);
  if (i < OUT_F4) out4[i] = z;
  else if (i < OUT_F4 + HIST_F4) hist4[i - OUT_F4] = z;
}

// ---------------------------------------------------------------------------
// Kernel 1: pack W (bf16 hi/lo) into STAGING order (blocks 0..255) +
// per-(b,n) matrix prep (block 256).
// Staging layout: flat = ((kb6*8 + half*4 + i)*128 + o)*8 + j holds
//   W[o][k = kb6*64 + half*32 + i*8 + j]
// ---------------------------------------------------------------------------
__device__ inline void inv3(const double a[9], double o[9]) {
  double c0 = a[4]*a[8] - a[5]*a[7];
  double c1 = a[3]*a[8] - a[5]*a[6];
  double c2 = a[3]*a[7] - a[4]*a[6];
  double det = a[0]*c0 - a[1]*c1 + a[2]*c2;
  double id = 1.0 / det;
  o[0] =  c0 * id;
  o[1] = (a[2]*a[7] - a[1]*a[8]) * id;
  o[2] = (a[1]*a[5] - a[2]*a[4]) * id;
  o[3] = -c1 * id;
  o[4] = (a[0]*a[8] - a[2]*a[6]) * id;
  o[5] = (a[2]*a[3] - a[0]*a[5]) * id;
  o[6] =  c2 * id;
  o[7] = (a[1]*a[6] - a[0]*a[7]) * id;
  o[8] = (a[0]*a[4] - a[1]*a[3]) * id;
}

__global__ __launch_bounds__(256) void prep_convw(
    const float* __restrict__ rots, const float* __restrict__ trans,
    const float* __restrict__ intr, const float* __restrict__ prot,
    const float* __restrict__ ptra, float* __restrict__ mats,
    const float* __restrict__ Wd, u16* __restrict__ PBh, u16* __restrict__ PBl) {
  if (blockIdx.x < 256) {
    int flat = blockIdx.x * 256 + threadIdx.x;   // 65536 entries
    int j    = flat & 7;
    int o    = (flat >> 3) & 127;
    int i    = (flat >> 10) & 3;
    int half = (flat >> 12) & 1;
    int kb6  = flat >> 13;                       // 0..7
    int k    = kb6 * 64 + half * 32 + i * 8 + j; // 0..511
    float f  = (o < 123) ? Wd[o * 512 + k] : 0.f;
    u16 h = f2bf(f);
    PBh[flat] = h;
    PBl[flat] = f2bf(f - bf2f(h));
    return;
  }
  int bn = threadIdx.x;
  if (bn >= NIMG) return;
  double pr[9], ik[9];
  for (int i = 0; i < 9; i++) { pr[i] = prot[bn*9 + i]; ik[i] = intr[bn*9 + i]; }
  double Minv[9], Kinv[9];
  inv3(pr, Minv);
  inv3(ik, Kinv);
  float* m = mats + bn*24;
  for (int i = 0; i < 9; i++) m[i] = (float)Minv[i];
  float kf[9];
  for (int i = 0; i < 9; i++) kf[i] = (float)Kinv[i];
  {
#pragma clang fp contract(off)
    for (int i = 0; i < 3; i++)
      for (int j = 0; j < 3; j++) {
        float s = rots[bn*9 + i*3 + 0] * kf[0*3 + j];
        s = s + rots[bn*9 + i*3 + 1] * kf[1*3 + j];
        s = s + rots[bn*9 + i*3 + 2] * kf[2*3 + j];
        m[9 + i*3 + j] = s;
      }
  }
  m[18] = ptra[bn*3 + 0]; m[19] = ptra[bn*3 + 1]; m[20] = ptra[bn*3 + 2];
  m[21] = trans[bn*3 + 0]; m[22] = trans[bn*3 + 1]; m[23] = trans[bn*3 + 2];
}

// ---------------------------------------------------------------------------
// Kernel 2: fused MFMA GEMM (bf16 hi/lo 3-term ~= fp32) + softmax.
// r12-validated structure; B staged from packed arrays (coalesced 16B/lane).
// ---------------------------------------------------------------------------
__global__ __launch_bounds__(256) void gemm_fused(const float* __restrict__ x,
    const u16* __restrict__ PBh, const u16* __restrict__ PBl,
    const float* __restrict__ bd,
    float* __restrict__ depth_ws, float* __restrict__ img_ws) {
  __shared__ __attribute__((aligned(16))) unsigned char smem[46080];
  int t = threadIdx.x;
  int l = t & 63, wid = t >> 6;
  int wr = wid >> 1, wc = wid & 1;
  int pixbase = blockIdx.x << 5;       // 704 = 22*32: tile stays in one image
  int bn = pixbase / NPIX;
  int pix0 = pixbase - bn * NPIX;
  const float* xb = x + (size_t)bn * 512 * NPIX + pix0;

  // Per-thread staging coords
  int a_c0   = (t & 15) << 2;          // 0..60 (c quad)
  int a_pixt = (t >> 4) << 1;          // 0..30 (pix pair)
  int b_o    = t & 127;
  int b_kh   = (t >> 7) << 5;          // 0 or 32

  // Prefetch registers
  float2 pa[4];
  u16x8 pbh[4], pbl[4];

#define LOADK(KB)                                                              \
  {                                                                            \
    pa[0] = *(const float2*)&xb[(size_t)((KB) + a_c0 + 0) * NPIX + a_pixt];    \
    pa[1] = *(const float2*)&xb[(size_t)((KB) + a_c0 + 1) * NPIX + a_pixt];    \
    pa[2] = *(const float2*)&xb[(size_t)((KB) + a_c0 + 2) * NPIX + a_pixt];    \
    pa[3] = *(const float2*)&xb[(size_t)((KB) + a_c0 + 3) * NPIX + a_pixt];    \
    size_t gb = ((((size_t)((KB) >> 6) << 3) + ((size_t)(t >> 7) << 2)) << 10) \
                + ((size_t)(t & 127) << 3);                                    \
    _Pragma("unroll")                                                          \
    for (int i = 0; i < 4; ++i) {                                              \
      pbh[i] = *(const u16x8*)(PBh + gb + ((size_t)i << 10));                  \
      pbl[i] = *(const u16x8*)(PBl + gb + ((size_t)i << 10));                  \
    }                                                                          \
  }

#define WRITEK()                                                               \
  {                                                                            \
    _Pragma("unroll")                                                          \
    for (int j = 0; j < 2; ++j) {                                              \
      float f0 = j ? pa[0].y : pa[0].x;                                        \
      float f1 = j ? pa[1].y : pa[1].x;                                        \
      float f2 = j ? pa[2].y : pa[2].x;                                        \
      float f3 = j ? pa[3].y : pa[3].x;                                        \
      __bf16 h0 = (__bf16)f0, h1 = (__bf16)f1, h2 = (__bf16)f2, h3 = (__bf16)f3;\
      bf16x4 hv = {h0, h1, h2, h3};                                            \
      bf16x4 lv = {(__bf16)(f0 - (float)h0), (__bf16)(f1 - (float)h1),         \
                   (__bf16)(f2 - (float)h2), (__bf16)(f3 - (float)h3)};        \
      int row = a_pixt + j;                                                    \
      *(bf16x4*)(smem + row * 144 + a_c0 * 2) = hv;                            \
      *(bf16x4*)(smem + 4608 + row * 144 + a_c0 * 2) = lv;                     \
    }                                                                          \
    _Pragma("unroll")                                                          \
    for (int i = 0; i < 4; ++i) {                                              \
      int kkb = (b_kh + (i << 3)) * 2;                                         \
      *(u16x8*)(smem + 9216 + b_o * 144 + kkb) = pbh[i];                       \
      *(u16x8*)(smem + 27648 + b_o * 144 + kkb) = pbl[i];                      \
    }                                                                          \
  }

  f32x4 zero4 = {0.f, 0.f, 0.f, 0.f};
  f32x4 acc[4];
#pragma unroll
  for (int ni = 0; ni < 4; ni++) acc[ni] = zero4;

  // Prologue: stage kb=0
  LOADK(0);
  WRITEK();
  __syncthreads();

  for (int kb = 0; kb < 512; kb += 64) {
    if (kb + 64 < 512) LOADK(kb + 64);   // issue next-tile loads early
    // ---- compute current tile: 2 k-halves x 4 frags x 3 MFMA ----
#pragma unroll
    for (int h = 0; h < 2; ++h) {
      int kk2 = (h * 32 + ((l >> 4) << 3)) * 2;     // byte offset in row
      int arow = (wr << 4) + (l & 15);
      bf16x8 ah = *(const bf16x8*)(smem + arow * 144 + kk2);
      bf16x8 al = *(const bf16x8*)(smem + 4608 + arow * 144 + kk2);
#pragma unroll
      for (int ni = 0; ni < 4; ++ni) {
        int o = (wc << 6) + (ni << 4) + (l & 15);
        bf16x8 bh_ = *(const bf16x8*)(smem + 9216 + o * 144 + kk2);
        bf16x8 bl_ = *(const bf16x8*)(smem + 27648 + o * 144 + kk2);
        acc[ni] = __builtin_amdgcn_mfma_f32_16x16x32_bf16(ah, bh_, acc[ni], 0, 0, 0);
        acc[ni] = __builtin_amdgcn_mfma_f32_16x16x32_bf16(ah, bl_, acc[ni], 0, 0, 0);
        acc[ni] = __builtin_amdgcn_mfma_f32_16x16x32_bf16(al, bh_, acc[ni], 0, 0, 0);
      }
    }
    __syncthreads();                     // all waves done reading LDS
    if (kb + 64 < 512) {
      WRITEK();                          // vmcnt-wait lands here, after compute
      __syncthreads();
    }
  }

  // ---- epilogue: acc -> F[32][132], then wave softmax ----
  float* F = (float*)smem;
#pragma unroll
  for (int ni = 0; ni < 4; ++ni)
#pragma unroll
    for (int r = 0; r < 4; ++r) {
      int row = (wr << 4) + ((l >> 4) << 2) + r;
      int col = (wc << 6) + (ni << 4) + (l & 15);
      F[row * 132 + col] = acc[ni][r];
    }
  __syncthreads();

  int c = l;
  float bA = bd[c];
  float bI = bd[DB + c];
  for (int p = wid; p < 32; p += 4) {
    float fA = F[p * 132 + c] + bA;
    float fI = F[p * 132 + DB + c] + bI;
    float mv = (c < DB) ? fA : -3.4e38f;
#pragma unroll
    for (int ofs = 32; ofs > 0; ofs >>= 1) mv = fmaxf(mv, __shfl_xor(mv, ofs));
    float ev = (c < DB) ? expf(fA - mv) : 0.f;
    float sv = ev;
#pragma unroll
    for (int ofs = 32; ofs > 0; ofs >>= 1) sv += __shfl_xor(sv, ofs);
    size_t rec = (size_t)(pixbase + p) << 6;
    if (c < DB) depth_ws[rec + c] = ev / sv;
    img_ws[rec + c] = fI;
  }
#undef LOADK
#undef WRITEK
}

// ---------------------------------------------------------------------------
// Kernel 3: geometry -> sliced key + rank via hist atomic.
// ---------------------------------------------------------------------------
__global__ __launch_bounds__(256) void geom_k(const float* __restrict__ mats,
    int2* __restrict__ pr, int* __restrict__ hist) {
  int wid = (blockIdx.x << 2) + (threadIdx.x >> 6);
  int lane = threadIdx.x & 63;
  int bn = wid / NPIX;
  int pix = wid - bn*NPIX;
  int b = bn / NCAM;
  int h = pix / 44, w = pix - h*44;
  const float* M = mats + bn*24;

  int code = -1;
  {
#pragma clang fp contract(off)
    float xs = (float)((double)w * (703.0 / 43.0));
    float ys = (float)(h * 17);
    float dval = (float)(lane + 1);
    float vx = xs - M[18], vy = ys - M[19], vz = dval - M[20];
    float qx = M[0]*vx + M[1]*vy + M[2]*vz;
    float qy = M[3]*vx + M[4]*vy + M[5]*vz;
    float qz = M[6]*vx + M[7]*vy + M[8]*vz;
    float rx = qx*qz, ry = qy*qz;
    float px = M[9]*rx  + M[10]*ry + M[11]*qz + M[21];
    float py = M[12]*rx + M[13]*ry + M[14]*qz + M[22];
    float pz = M[15]*rx + M[16]*ry + M[17]*qz + M[23];
    float gx = floorf((px - (-50.8f - 0.4f)) / 0.8f);
    float gy = floorf((py - (-50.8f - 0.4f)) / 0.8f);
    float gz = floorf((pz - (0.0f - 10.0f)) / 20.0f);
    bool kept = (lane < DB) && (gx >= 0.f) && (gx < 128.f) &&
                (gy >= 0.f) && (gy < 128.f) && (gz == 0.f);
    if (kept) code = (b << 14) + (int)gy * 128 + (int)gx;
  }

  if (lane < DB) {
    int key = -1, r = 0;
    if (code >= 0) {
      key = code * SLC + ((wid + lane) & (SLC - 1));
      r = atomicAdd(&hist[key], 1);
    }
    pr[(size_t)wid * DB + lane] = make_int2(key, r);
  }
}

// ---------------------------------------------------------------------------
// Kernels 4a/4b/4c: hierarchical exclusive scan of hist[NKEY].
// ---------------------------------------------------------------------------
__global__ __launch_bounds__(256) void scan1_k(const int* __restrict__ hist,
    int* __restrict__ blockSums) {
  __shared__ int red[256];
  int t = threadIdx.x;
  const int4* h4 = (const int4*)(hist + (blockIdx.x << 10));
  int4 v = h4[t];
  red[t] = v.x + v.y + v.z + v.w;
  __syncthreads();
  for (int ofs = 128; ofs > 0; ofs >>= 1) {
    if (t < ofs) red[t] += red[t + ofs];
    __syncthreads();
  }
  if (t == 0) blockSums[blockIdx.x] = red[0];
}

__global__ __launch_bounds__(512) void scan2_k(int* __restrict__ blockSums,
    int* __restrict__ totalK) {
  __shared__ int buf[2][512];
  int t = threadIdx.x;
  buf[0][t] = blockSums[t];
  __syncthreads();
  int src = 0;
  for (int ofs = 1; ofs < 512; ofs <<= 1) {
    int v = buf[src][t];
    if (t >= ofs) v += buf[src][t - ofs];
    buf[src ^ 1][t] = v;
    __syncthreads();
    src ^= 1;
  }
  blockSums[t] = (t == 0) ? 0 : buf[src][t - 1];
  if (t == 511) *totalK = buf[src][511];
}

__global__ __launch_bounds__(256) void scan3_k(int* __restrict__ hist,
    const int* __restrict__ blockSums) {
  __shared__ int buf[2][256];
  int t = threadIdx.x;
  int4* h4 = (int4*)(hist + (blockIdx.x << 10));
  int4 v = h4[t];
  int s = v.x + v.y + v.z + v.w;
  buf[0][t] = s;
  __syncthreads();
  int src = 0;
  for (int ofs = 1; ofs < 256; ofs <<= 1) {
    int vv = buf[src][t];
    if (t >= ofs) vv += buf[src][t - ofs];
    buf[src ^ 1][t] = vv;
    __syncthreads();
    src ^= 1;
  }
  int run = blockSums[blockIdx.x] + ((t == 0) ? 0 : buf[src][t - 1]);
  int4 o;
  o.x = run; run += v.x;
  o.y = run; run += v.y;
  o.z = run; run += v.z;
  o.w = run;
  h4[t] = o;
}

// ---------------------------------------------------------------------------
// Kernel 5: atomic-free placement: pos = offsets[key] + rank.
// ---------------------------------------------------------------------------
__global__ __launch_bounds__(256) void order_k(const int2* __restrict__ pr,
    const int* __restrict__ offsets, int2* __restrict__ sorted) {
  int p = blockIdx.x * 256 + threadIdx.x;
  if (p >= P_TOT) return;
  int2 e = pr[p];
  if (e.x >= 0) {
    int pos = offsets[e.x] + e.y;
    int bnpix = p / DB;
    int d = p - bnpix * DB;
    sorted[pos] = make_int2(e.x / SLC, (bnpix << 6) + d);
  }
}

// ---------------------------------------------------------------------------
// Kernel 6: segmented gather. One wave per CHUNK sorted points; lane = channel.
// ---------------------------------------------------------------------------
__global__ __launch_bounds__(256) void gather_seg(const int2* __restrict__ sorted,
    const int* __restrict__ totalK,
    const float* __restrict__ depth_ws, const float* __restrict__ img_ws,
    float* __restrict__ out) {
  int wid = (blockIdx.x << 2) + (threadIdx.x >> 6);
  int lane = threadIdx.x & 63;
  int K = *totalK;
  int start = wid * CHUNK;
  if (start >= K) return;
  int end = min(start + CHUNK, K);

  int2 s0 = sorted[start];
  int cur = s0.x;
  float acc = 0.f;
  for (int i = start; i < end; ++i) {
    int2 s = sorted[i];
    if (s.x != cur) {                     // wave-uniform branch
      int b = cur >> 14, vox = cur & 16383;
      unsafeAtomicAdd(&out[((size_t)((b << 6) + lane) << 14) + vox], acc);
      acc = 0.f;
      cur = s.x;
    }
    float dep = depth_ws[s.y];                          // broadcast load
    float im  = img_ws[(s.y & 0x7FFFFFC0) + lane];      // coalesced 256B
    acc += dep * im;
  }
  int b = cur >> 14, vox = cur & 16383;
  unsafeAtomicAdd(&out[((size_t)((b << 6) + lane) << 14) + vox], acc);
}

// ---------------------------------------------------------------------------
extern "C" void kernel_launch(void* const* d_in, const int* in_sizes, int n_in,
                              void* d_out, int out_size, void* d_ws, size_t ws_size,
                              hipStream_t stream) {
  const float* x    = (const float*)d_in[0];
  const float* rots = (const float*)d_in[1];
  const float* trn  = (const float*)d_in[2];
  const float* intr = (const float*)d_in[3];
  const float* prot = (const float*)d_in[4];
  const float* ptra = (const float*)d_in[5];
  const float* Wd   = (const float*)d_in[6];
  const float* bd   = (const float*)d_in[7];
  float* out = (float*)d_out;
  float* ws  = (float*)d_ws;

  // Layout identical in extent to the validated round-6..14 footprint.
  float* mats     = ws;                                    // 1024 floats
  float* depth_ws = ws + 1024;                             // 1,081,344
  float* img_ws   = depth_ws + (size_t)MPIX*64;            // 1,081,344
  int*   hist     = (int*)(img_ws + (size_t)MPIX*64);      // 524,288 (16B-aligned)
  int*   blockSums= hist + NKEY;                           // 512
  int*   totalK   = blockSums + 512;                       // 4 (pad)
  int2*  pr       = (int2*)(totalK + 4);                   // 996,864 int2
  int2*  sorted   = pr + P_TOT;                            // 996,864 int2
  // Packed-W (256 KB) aliases the head of hist's 2 MB: read only by
  // gemm_fused, which completes (stream order) before zero_ws clears hist.
  u16*   PBh      = (u16*)hist;                            // 65,536 u16
  u16*   PBl      = PBh + 65536;                           // 65,536 u16

  prep_convw<<<257, 256, 0, stream>>>(rots, trn, intr, prot, ptra, mats, Wd, PBh, PBl);
  gemm_fused<<<MPIX/32, 256, 0, stream>>>(x, PBh, PBl, bd, depth_ws, img_ws);
  zero_ws<<<(OUT_F4 + HIST_F4 + 255)/256, 256, 0, stream>>>((float4*)out, (float4*)hist);
  geom_k<<<NIMG*NPIX/4, 256, 0, stream>>>(mats, pr, hist);
  scan1_k<<<SCAN_BLKS, 256, 0, stream>>>(hist, blockSums);
  scan2_k<<<1, 512, 0, stream>>>(blockSums, totalK);
  scan3_k<<<SCAN_BLKS, 256, 0, stream>>>(hist, blockSums);
  order_k<<<(P_TOT + 255)/256, 256, 0, stream>>>(pr, hist, sorted);
  gather_seg<<<(P_TOT/CHUNK + 3)/4, 256, 0, stream>>>(sorted, totalK, depth_ws, img_ws, out);
}